// Round 3
// baseline (501.282 us; speedup 1.0000x reference)
//
#include <hip/hip_runtime.h>

typedef unsigned short us;
typedef short s16x8 __attribute__((ext_vector_type(8)));
typedef float f32x4 __attribute__((ext_vector_type(4)));

__device__ __forceinline__ us f2bf(float f) {
  union { float f; unsigned u; } v; v.f = f;
  unsigned u = v.u;
  u += 0x7fffu + ((u >> 16) & 1u);   // RNE
  return (us)(u >> 16);
}
__device__ __forceinline__ float bf2f(us u) {
  union { unsigned u; float f; } v; v.u = ((unsigned)u) << 16; return v.f;
}
__device__ __forceinline__ s16x8 ld8(const us* p) { return *(const s16x8*)p; }

#define MFMA(a, b, c) __builtin_amdgcn_mfma_f32_16x16x32_bf16(a, b, c, 0, 0, 0)

// wave-local LDS fence: all prior ds ops complete (visible CU-wide), compiler
// may not move memory ops across it. Replaces __syncthreads for per-wave data.
__device__ __forceinline__ void lds_fence() {
  asm volatile("s_waitcnt lgkmcnt(0)" ::: "memory");
}

__device__ __forceinline__ float qsum(float v) {
  v += __shfl_xor(v, 1, 64); v += __shfl_xor(v, 2, 64);
  v += __shfl_xor(v, 4, 64); v += __shfl_xor(v, 8, 64);
  return v;
}
__device__ __forceinline__ float qmax(float v) {
  v = fmaxf(v, __shfl_xor(v, 1, 64)); v = fmaxf(v, __shfl_xor(v, 2, 64));
  v = fmaxf(v, __shfl_xor(v, 4, 64)); v = fmaxf(v, __shfl_xor(v, 8, 64));
  return v;
}
__device__ __forceinline__ int cls3(int v) { return v < 120 ? 0 : (v < 124 ? 1 : 2); }

// fast exact-erf GELU: A&S 7.1.26, |err(erf)| <= 1.5e-7
__device__ __forceinline__ float gelu_fast(float x) {
  float ax = fabsf(x);
  float t = __builtin_amdgcn_rcpf(1.f + 0.3275911f * ax);
  float p = t * (0.254829592f +
            t * (-0.284496736f +
            t * (1.421413741f +
            t * (-1.453152027f +
            t * 1.061405429f))));
  float e = __expf(-ax * ax);
  float er = copysignf(1.f - p * e, x);
  return 0.5f * x * (1.f + er);
}

// ---------- prep: all weight swizzles + rpb table expansion in one launch.
// B-swizzle: dst[((k>>3)*N + n)*8 + (k&7)] = bf16(W[n][k]) -> B-frag = one 16B load.
__global__ void prep_kernel(const float* __restrict__ qkv_w, const float* __restrict__ proj_w,
                            const float* __restrict__ fc1_w, const float* __restrict__ fc2_w,
                            const float* __restrict__ rpb_table,
                            us* __restrict__ qkvw, us* __restrict__ projw,
                            us* __restrict__ fc1w, us* __restrict__ fc2w,
                            us* __restrict__ rpbh) {
  int id = blockIdx.x * 256 + threadIdx.x;
  if (id < 49152) {  // qkv (384,128); fold q-scale into Q cols (n<128)
    int n = id % 384, k = id / 384;
    float v = qkv_w[n * 128 + k];
    if (n < 128) v *= 0.17677669529663687f;
    qkvw[(((k >> 3) * 384 + n) << 3) + (k & 7)] = f2bf(v);
    return;
  }
  id -= 49152;
  if (id < 16384) { int n = id % 128, k = id / 128;
    projw[(((k >> 3) * 128 + n) << 3) + (k & 7)] = f2bf(proj_w[n * 128 + k]); return; }
  id -= 16384;
  if (id < 65536) { int n = id % 512, k = id / 512;
    fc1w[(((k >> 3) * 512 + n) << 3) + (k & 7)] = f2bf(fc1_w[n * 128 + k]); return; }
  id -= 65536;
  if (id < 65536) { int n = id % 128, k = id / 128;
    fc2w[(((k >> 3) * 128 + n) << 3) + (k & 7)] = f2bf(fc2_w[n * 512 + k]); return; }
  id -= 65536;
  {  // rpbh[h][n1][n2] bf16
    int h = id >> 12, e = id & 4095, n1 = e >> 6, n2 = e & 63;
    int idx = ((n1 >> 3) - (n2 >> 3) + 7) * 15 + ((n1 & 7) - (n2 & 7) + 7);
    rpbh[id] = f2bf(rpb_table[idx * 4 + h]);
  }
}

// ---------- K1: per window: gather+roll (ONCE) -> QKV GEMM all heads -> Q/K/V global bf16
__global__ __launch_bounds__(256) void qkv_kernel(
    const float* __restrict__ x_v, const us* __restrict__ qkvw,
    const float* __restrict__ qkv_b,
    us* __restrict__ Qg, us* __restrict__ Kg, us* __restrict__ Vg) {
  __shared__ __align__(16) us A[128 * 136];  // 34816 B
  int w = blockIdx.x;
  int b = w >> 8, wi = w & 255, wh = wi >> 4, ww = wi & 15;
  int tid = threadIdx.x;

  { // gather: rolled(p) = orig((p+4)&127)
    int token = tid >> 1, half = tid & 1;
    int t = token >> 6, n = token & 63, r = n >> 3, c = n & 7;
    int hs = (wh * 8 + r + 4) & 127, wsc = (ww * 8 + c + 4) & 127;
    const float* src = x_v + (size_t)((b * 2 + t) * 16384 + hs * 128 + wsc) * 128 + half * 64;
    us* dst = A + token * 136 + half * 64;
#pragma unroll
    for (int i = 0; i < 8; ++i) {
      float4 f0 = ((const float4*)src)[2 * i];
      float4 f1 = ((const float4*)src)[2 * i + 1];
      s16x8 v;
      v[0] = (short)f2bf(f0.x); v[1] = (short)f2bf(f0.y);
      v[2] = (short)f2bf(f0.z); v[3] = (short)f2bf(f0.w);
      v[4] = (short)f2bf(f1.x); v[5] = (short)f2bf(f1.y);
      v[6] = (short)f2bf(f1.z); v[7] = (short)f2bf(f1.w);
      *(s16x8*)(dst + i * 8) = v;
    }
  }
  __syncthreads();

  int lane = tid & 63, h = tid >> 6, quad = lane >> 4, c16 = lane & 15;
  size_t wb = (size_t)(w * 4 + h) * 4096;

#pragma unroll
  for (int p = 0; p < 2; ++p) {  // row passes: 64 rows each
    int rb = p * 64;
    f32x4 acc[4][6];
#pragma unroll
    for (int mi = 0; mi < 4; ++mi)
#pragma unroll
      for (int ni = 0; ni < 6; ++ni) acc[mi][ni] = (f32x4){0.f, 0.f, 0.f, 0.f};
#pragma unroll
    for (int ks = 0; ks < 4; ++ks) {
      int k0 = ks * 32;
      s16x8 af[4];
#pragma unroll
      for (int mi = 0; mi < 4; ++mi)
        af[mi] = ld8(A + (rb + mi * 16 + c16) * 136 + k0 + quad * 8);
#pragma unroll
      for (int ni = 0; ni < 6; ++ni) {
        int gcol = (ni >> 1) * 128 + h * 32 + (ni & 1) * 16 + c16;
        s16x8 bf = ld8(qkvw + ((((k0 >> 3) + quad) * 384 + gcol) << 3));
#pragma unroll
        for (int mi = 0; mi < 4; ++mi) acc[mi][ni] = MFMA(af[mi], bf, acc[mi][ni]);
      }
    }
#pragma unroll
    for (int ni = 0; ni < 6; ++ni) {
      int part = ni >> 1, colh = (ni & 1) * 16 + c16;
      float bias = qkv_b[part * 128 + h * 32 + colh];
      if (part == 0) bias *= 0.17677669529663687f;
      us* dstp = (part == 0) ? Qg : (part == 1) ? Kg : Vg;
#pragma unroll
      for (int mi = 0; mi < 4; ++mi)
#pragma unroll
        for (int r = 0; r < 4; ++r) {
          int tok = rb + mi * 16 + quad * 4 + r;
          dstp[wb + tok * 32 + colh] = f2bf(acc[mi][ni][r] + bias);
        }
    }
  }
}

// ---------- K2: per (window, head) attention on precomputed Q/K/V
__global__ __launch_bounds__(256) void attn_kernel2(
    const us* __restrict__ Qg, const us* __restrict__ Kg, const us* __restrict__ Vg,
    const us* __restrict__ rpbh, us* __restrict__ attn_out) {
  __shared__ __align__(16) unsigned char smem[46592];
  us* Kb = (us*)smem;                 // [128][40]  10240 B
  us* Vb = (us*)(smem + 10240);       // [128][40]  10240 B
  us* rpbL = (us*)(smem + 20480);     // [64][64] bf16 8192 B (+pad)
  // Pw per-wave at 29184 + wv*4352   // [16][136]

  int bid = blockIdx.x;
  int w = bid >> 2, h = bid & 3;
  int wi = w & 255, wh = wi >> 4, ww = wi & 15;
  int tid = threadIdx.x;
  size_t wb = (size_t)(w * 4 + h) * 4096;

  {  // stage K, V: [128][32] -> LDS stride 40
#pragma unroll
    for (int kk = 0; kk < 2; ++kk) {
      int idx = tid + kk * 256;           // 512 chunks of 8 us
      int row = idx >> 2, c8 = (idx & 3) * 8;
      *(s16x8*)(Kb + row * 40 + c8) = ld8(Kg + wb + row * 32 + c8);
      *(s16x8*)(Vb + row * 40 + c8) = ld8(Vg + wb + row * 32 + c8);
    }
    // stage rpb bf16: 4096 us = 512 chunks
#pragma unroll
    for (int kk = 0; kk < 2; ++kk) {
      int idx = tid + kk * 256;
      *(s16x8*)(rpbL + idx * 8) = ld8(rpbh + h * 4096 + idx * 8);
    }
  }
  __syncthreads();

  int lane = tid & 63, wv = tid >> 6, quad = lane >> 4, c16 = lane & 15;
  us* Pw = (us*)(smem + 29184 + wv * 4352);

#pragma unroll
  for (int qc = 0; qc < 2; ++qc) {
    int q0 = wv * 32 + qc * 16;
    // Q fragment direct from global (each row read exactly once chip-wide)
    s16x8 aq = ld8(Qg + wb + (q0 + c16) * 32 + quad * 8);
    f32x4 sacc[8];
#pragma unroll
    for (int nj = 0; nj < 8; ++nj) {
      s16x8 bk = ld8(Kb + (nj * 16 + c16) * 40 + quad * 8);
      sacc[nj] = MFMA(aq, bk, ((f32x4){0.f, 0.f, 0.f, 0.f}));
    }
    // per-row class (hoisted) + rpb + mask + softmax
    int cq[4], nqv[4];
#pragma unroll
    for (int r = 0; r < 4; ++r) {
      int qt = q0 + quad * 4 + r, nq = qt & 63;
      nqv[r] = nq;
      cq[r] = cls3(wh * 8 + (nq >> 3)) * 3 + cls3(ww * 8 + (nq & 7));
    }
    float mx[4] = {-1e30f, -1e30f, -1e30f, -1e30f};
#pragma unroll
    for (int nj = 0; nj < 8; ++nj) {
      int nk = (nj * 16 + c16) & 63;
      int ck = cls3(wh * 8 + (nk >> 3)) * 3 + cls3(ww * 8 + (nk & 7));
#pragma unroll
      for (int r = 0; r < 4; ++r) {
        float s = sacc[nj][r] + bf2f(rpbL[nqv[r] * 64 + nk]) + (cq[r] != ck ? -100.f : 0.f);
        sacc[nj][r] = s;
        mx[r] = fmaxf(mx[r], s);
      }
    }
#pragma unroll
    for (int r = 0; r < 4; ++r) mx[r] = qmax(mx[r]);
    float sm[4] = {0.f, 0.f, 0.f, 0.f};
#pragma unroll
    for (int nj = 0; nj < 8; ++nj)
#pragma unroll
      for (int r = 0; r < 4; ++r) {
        float p = __expf(sacc[nj][r] - mx[r]);
        sacc[nj][r] = p;
        sm[r] += p;
      }
    float inv[4];
#pragma unroll
    for (int r = 0; r < 4; ++r) inv[r] = 1.f / qsum(sm[r]);
    // P -> per-wave LDS (C-layout -> A-layout round trip)
#pragma unroll
    for (int nj = 0; nj < 8; ++nj)
#pragma unroll
      for (int r = 0; r < 4; ++r)
        Pw[(quad * 4 + r) * 136 + nj * 16 + c16] = f2bf(sacc[nj][r] * inv[r]);
    lds_fence();
    // PV: B-frag built from row-major V via scalar LDS reads
    f32x4 oacc[2];
    oacc[0] = (f32x4){0.f, 0.f, 0.f, 0.f};
    oacc[1] = (f32x4){0.f, 0.f, 0.f, 0.f};
#pragma unroll
    for (int ks = 0; ks < 4; ++ks) {
      int k0 = ks * 32;
      s16x8 ap = ld8(Pw + c16 * 136 + k0 + quad * 8);
#pragma unroll
      for (int nt = 0; nt < 2; ++nt) {
        s16x8 bv;
#pragma unroll
        for (int j = 0; j < 8; ++j)
          bv[j] = (short)Vb[(k0 + quad * 8 + j) * 40 + nt * 16 + c16];
        oacc[nt] = MFMA(ap, bv, oacc[nt]);
      }
    }
#pragma unroll
    for (int nt = 0; nt < 2; ++nt)
#pragma unroll
      for (int r = 0; r < 4; ++r) {
        int tok = q0 + quad * 4 + r;
        attn_out[((size_t)w * 128 + tok) * 128 + h * 32 + nt * 16 + c16] =
            f2bf(oacc[nt][r]);
      }
    lds_fence();  // Pw WAR before next qc
  }
}

// ---------- K3: barrier-free fused proj+LN2+MLP+LN1. Wave owns 16 tokens.
__global__ __launch_bounds__(256) void fused_kernel2(
    const us* __restrict__ attn_ws, const us* __restrict__ projw,
    const float* __restrict__ proj_b, const float* __restrict__ x_v,
    const us* __restrict__ fc1w, const us* __restrict__ fc2w,
    const float* __restrict__ fc1_b, const float* __restrict__ fc2_b,
    const float* __restrict__ n2w, const float* __restrict__ n2b,
    const float* __restrict__ n1w, const float* __restrict__ n1b,
    float* __restrict__ out) {
  __shared__ __align__(16) unsigned char smem[34816];
  int bid = blockIdx.x;
  int w = bid >> 1, h64 = (bid & 1) * 64;
  int b = w >> 8, wi = w & 255, wh = wi >> 4, ww = wi & 15;
  int tid = threadIdx.x;
  int lane = tid & 63, wv = tid >> 6, quad = lane >> 4, c16 = lane & 15;

  us* Xw = (us*)(smem + wv * 4352);           // [16][136] attn tile -> LN2'd x
  us* Hw = (us*)(smem + 17408 + wv * 4352);   // [16][136] gelu chunk

  {  // wave stages its OWN 16 rows (no cross-wave dependency)
    int row = lane >> 2, q32 = (lane & 3) * 32;
    const us* src = attn_ws + ((size_t)w * 128 + h64 + wv * 16 + row) * 128 + q32;
    us* dst = Xw + row * 136 + q32;
    *(s16x8*)(dst) = ld8(src);
    *(s16x8*)(dst + 8) = ld8(src + 8);
    *(s16x8*)(dst + 16) = ld8(src + 16);
    *(s16x8*)(dst + 24) = ld8(src + 24);
  }

  // residual addresses + prefetch x_v (hidden behind proj MFMAs)
  size_t grow[4];
#pragma unroll
  for (int r = 0; r < 4; ++r) {
    int tt = h64 + wv * 16 + quad * 4 + r;
    int t = tt >> 6, n = tt & 63, rr = n >> 3, cc2 = n & 7;
    int hf = (wh * 8 + rr + 4) & 127, wf = (ww * 8 + cc2 + 4) & 127;
    grow[r] = (size_t)((b * 2 + t) * 16384 + hf * 128 + wf) * 128;
  }
  float xv[4][8];
#pragma unroll
  for (int r = 0; r < 4; ++r)
#pragma unroll
    for (int ni = 0; ni < 8; ++ni) xv[r][ni] = x_v[grow[r] + ni * 16 + c16];

  lds_fence();  // staging visible to own wave

  // ---- proj: 16 rows x 128 cols, K=128
  f32x4 y[8];
#pragma unroll
  for (int ni = 0; ni < 8; ++ni) y[ni] = (f32x4){0.f, 0.f, 0.f, 0.f};
#pragma unroll
  for (int ks = 0; ks < 4; ++ks) {
    int k0 = ks * 32;
    s16x8 af = ld8(Xw + c16 * 136 + k0 + quad * 8);
#pragma unroll
    for (int ni = 0; ni < 8; ++ni) {
      s16x8 bf = ld8(projw + ((((k0 >> 3) + quad) * 128 + ni * 16 + c16) << 3));
      y[ni] = MFMA(af, bf, y[ni]);
    }
  }

  // ---- y += proj_b + shortcut; LN2 stats within wave
  float sum[4] = {0.f, 0.f, 0.f, 0.f}, sq[4] = {0.f, 0.f, 0.f, 0.f};
#pragma unroll
  for (int ni = 0; ni < 8; ++ni) {
    float pb = proj_b[ni * 16 + c16];
#pragma unroll
    for (int r = 0; r < 4; ++r) {
      float v = y[ni][r] + pb + xv[r][ni];
      y[ni][r] = v;
      sum[r] += v; sq[r] += v * v;
    }
  }
  float mean[4], rstd[4];
#pragma unroll
  for (int r = 0; r < 4; ++r) {
    float s = qsum(sum[r]), q = qsum(sq[r]);
    mean[r] = s * 0.0078125f;
    float var = q * 0.0078125f - mean[r] * mean[r];
    rstd[r] = rsqrtf(var + 1e-5f);
  }
  // LN2'd x -> Xw (overwrite; proj A-frags already consumed via data dep)
#pragma unroll
  for (int ni = 0; ni < 8; ++ni) {
    int col = ni * 16 + c16;
    float w2 = n2w[col], b2 = n2b[col];
#pragma unroll
    for (int r = 0; r < 4; ++r)
      Xw[(quad * 4 + r) * 136 + col] = f2bf((y[ni][r] - mean[r]) * rstd[r] * w2 + b2);
  }
  lds_fence();

  // ---- MLP: 8 chunks of 64 hidden cols; fc1 -> gelu -> fc2, all wave-local
  f32x4 o[8];
#pragma unroll
  for (int ni = 0; ni < 8; ++ni) o[ni] = (f32x4){0.f, 0.f, 0.f, 0.f};

  for (int cc = 0; cc < 8; ++cc) {
    f32x4 f[4];
#pragma unroll
    for (int ni = 0; ni < 4; ++ni) f[ni] = (f32x4){0.f, 0.f, 0.f, 0.f};
#pragma unroll
    for (int ks = 0; ks < 4; ++ks) {
      int k0 = ks * 32;
      s16x8 af = ld8(Xw + c16 * 136 + k0 + quad * 8);
#pragma unroll
      for (int ni = 0; ni < 4; ++ni) {
        s16x8 bf = ld8(fc1w + ((((k0 >> 3) + quad) * 512 + cc * 64 + ni * 16 + c16) << 3));
        f[ni] = MFMA(af, bf, f[ni]);
      }
    }
#pragma unroll
    for (int ni = 0; ni < 4; ++ni) {
      float bb = fc1_b[cc * 64 + ni * 16 + c16];
#pragma unroll
      for (int r = 0; r < 4; ++r) {
        float u = f[ni][r] + bb;
        Hw[(quad * 4 + r) * 136 + ni * 16 + c16] = f2bf(gelu_fast(u));
      }
    }
    lds_fence();
#pragma unroll
    for (int ks2 = 0; ks2 < 2; ++ks2) {
      int kg = cc * 64 + ks2 * 32;
      s16x8 af = ld8(Hw + c16 * 136 + ks2 * 32 + quad * 8);
#pragma unroll
      for (int ni = 0; ni < 8; ++ni) {
        s16x8 bf = ld8(fc2w + ((((kg >> 3) + quad) * 128 + ni * 16 + c16) << 3));
        o[ni] = MFMA(af, bf, o[ni]);
      }
    }
    lds_fence();  // Hw WAR before next chunk
  }

  // ---- z = fc2 + bias + y; LN1; scatter store
  float s1[4] = {0.f, 0.f, 0.f, 0.f}, q1[4] = {0.f, 0.f, 0.f, 0.f};
#pragma unroll
  for (int ni = 0; ni < 8; ++ni) {
    float fb = fc2_b[ni * 16 + c16];
#pragma unroll
    for (int r = 0; r < 4; ++r) {
      float v = o[ni][r] + fb + y[ni][r];
      y[ni][r] = v;
      s1[r] += v; q1[r] += v * v;
    }
  }
#pragma unroll
  for (int r = 0; r < 4; ++r) {
    float s = qsum(s1[r]), q = qsum(q1[r]);
    mean[r] = s * 0.0078125f;
    float var = q * 0.0078125f - mean[r] * mean[r];
    rstd[r] = rsqrtf(var + 1e-5f);
  }
#pragma unroll
  for (int ni = 0; ni < 8; ++ni) {
    int col = ni * 16 + c16;
    float w1 = n1w[col], b1 = n1b[col];
#pragma unroll
    for (int r = 0; r < 4; ++r)
      out[grow[r] + col] = (y[ni][r] - mean[r]) * rstd[r] * w1 + b1;
  }
}

extern "C" void kernel_launch(void* const* d_in, const int* in_sizes, int n_in,
                              void* d_out, int out_size, void* d_ws, size_t ws_size,
                              hipStream_t stream) {
  const float* x_v   = (const float*)d_in[0];
  const float* qkv_w = (const float*)d_in[1];
  const float* qkv_b = (const float*)d_in[2];
  const float* proj_w = (const float*)d_in[3];
  const float* proj_b = (const float*)d_in[4];
  const float* rpb_t = (const float*)d_in[5];
  const float* n1w = (const float*)d_in[6];
  const float* n1b = (const float*)d_in[7];
  const float* n2w = (const float*)d_in[8];
  const float* n2b = (const float*)d_in[9];
  const float* fc1_w = (const float*)d_in[10];
  const float* fc1_b = (const float*)d_in[11];
  const float* fc2_w = (const float*)d_in[12];
  const float* fc2_b = (const float*)d_in[13];

  char* ws = (char*)d_ws;
  us* qkvw    = (us*)(ws + 0);         //  98304
  us* projw   = (us*)(ws + 98304);     //  32768
  us* fc1w    = (us*)(ws + 131072);    // 131072
  us* fc2w    = (us*)(ws + 262144);    // 131072
  us* rpbh    = (us*)(ws + 393216);    //  32768
  us* Qg      = (us*)(ws + 425984);    // 8388608
  us* Kg      = (us*)(ws + 8814592);   // 8388608
  us* Vg      = (us*)(ws + 17203200);  // 8388608
  us* attn_ws = (us*)(ws + 25591808);  // 33554432

  prep_kernel<<<832, 256, 0, stream>>>(qkv_w, proj_w, fc1_w, fc2_w, rpb_t,
                                       qkvw, projw, fc1w, fc2w, rpbh);
  qkv_kernel<<<1024, 256, 0, stream>>>(x_v, qkvw, qkv_b, Qg, Kg, Vg);
  attn_kernel2<<<4096, 256, 0, stream>>>(Qg, Kg, Vg, rpbh, attn_ws);
  fused_kernel2<<<2048, 256, 0, stream>>>(attn_ws, projw, proj_b, x_v,
                                          fc1w, fc2w, fc1_b, fc2_b,
                                          n2w, n2b, n1w, n1b, (float*)d_out);
}

// Round 4
// 357.165 us; speedup vs baseline: 1.4035x; 1.4035x over previous
//
#include <hip/hip_runtime.h>

typedef unsigned short us;
typedef short s16x8 __attribute__((ext_vector_type(8)));
typedef float f32x4 __attribute__((ext_vector_type(4)));

__device__ __forceinline__ us f2bf(float f) {
  union { float f; unsigned u; } v; v.f = f;
  unsigned u = v.u;
  u += 0x7fffu + ((u >> 16) & 1u);   // RNE
  return (us)(u >> 16);
}
__device__ __forceinline__ float bf2f(us u) {
  union { unsigned u; float f; } v; v.u = ((unsigned)u) << 16; return v.f;
}
__device__ __forceinline__ s16x8 ld8(const us* p) { return *(const s16x8*)p; }

#define MFMA(a, b, c) __builtin_amdgcn_mfma_f32_16x16x32_bf16(a, b, c, 0, 0, 0)

// wave-local LDS fence: drain this wave's LDS ops; no cross-wave barrier.
__device__ __forceinline__ void lds_fence() {
  asm volatile("s_waitcnt lgkmcnt(0)" ::: "memory");
}

__device__ __forceinline__ float qsum(float v) {
  v += __shfl_xor(v, 1, 64); v += __shfl_xor(v, 2, 64);
  v += __shfl_xor(v, 4, 64); v += __shfl_xor(v, 8, 64);
  return v;
}

// fast exact-erf GELU: A&S 7.1.26, |err(erf)| <= 1.5e-7
__device__ __forceinline__ float gelu_fast(float x) {
  float ax = fabsf(x);
  float t = __builtin_amdgcn_rcpf(1.f + 0.3275911f * ax);
  float p = t * (0.254829592f +
            t * (-0.284496736f +
            t * (1.421413741f +
            t * (-1.453152027f +
            t * 1.061405429f))));
  float e = __expf(-ax * ax);
  float er = copysignf(1.f - p * e, x);
  return 0.5f * x * (1.f + er);
}

// ---------- prep: weight swizzles + combined rpb+mask tables.
// B-swizzle: dst[((k>>3)*N + n)*8 + (k&7)] = bf16(W[n][k]) -> B-frag = one 16B load.
// rpbm[h][cls][n1][n2] = bf16(rpb + mask), cls = (wh==15)*2 + (ww==15).
__global__ void prep_kernel(const float* __restrict__ qkv_w, const float* __restrict__ proj_w,
                            const float* __restrict__ fc1_w, const float* __restrict__ fc2_w,
                            const float* __restrict__ rpb_table,
                            us* __restrict__ qkvw, us* __restrict__ projw,
                            us* __restrict__ fc1w, us* __restrict__ fc2w,
                            us* __restrict__ rpbm) {
  int id = blockIdx.x * 256 + threadIdx.x;
  if (id < 49152) {  // qkv (384,128); fold q-scale into Q cols (n<128)
    int n = id % 384, k = id / 384;
    float v = qkv_w[n * 128 + k];
    if (n < 128) v *= 0.17677669529663687f;
    qkvw[(((k >> 3) * 384 + n) << 3) + (k & 7)] = f2bf(v);
    return;
  }
  id -= 49152;
  if (id < 16384) { int n = id % 128, k = id / 128;
    projw[(((k >> 3) * 128 + n) << 3) + (k & 7)] = f2bf(proj_w[n * 128 + k]); return; }
  id -= 16384;
  if (id < 65536) { int n = id % 512, k = id / 512;
    fc1w[(((k >> 3) * 512 + n) << 3) + (k & 7)] = f2bf(fc1_w[n * 128 + k]); return; }
  id -= 65536;
  if (id < 65536) { int n = id % 128, k = id / 128;
    fc2w[(((k >> 3) * 128 + n) << 3) + (k & 7)] = f2bf(fc2_w[n * 512 + k]); return; }
  id -= 65536;
  {
    int h = id >> 14, cls = (id >> 12) & 3, e = id & 4095;
    int n1 = e >> 6, n2 = e & 63;
    int r1 = n1 >> 3, c1 = n1 & 7, r2 = n2 >> 3, c2 = n2 & 7;
    int cH = cls >> 1, cW = cls & 1;
    int cq = (cH ? (r1 < 4 ? 1 : 2) : 0) * 3 + (cW ? (c1 < 4 ? 1 : 2) : 0);
    int ck = (cH ? (r2 < 4 ? 1 : 2) : 0) * 3 + (cW ? (c2 < 4 ? 1 : 2) : 0);
    int ridx = (r1 - r2 + 7) * 15 + (c1 - c2 + 7);
    float v = rpb_table[ridx * 4 + h] + (cq != ck ? -100.f : 0.f);
    rpbm[id] = f2bf(v);
  }
}

// ---------- K1: per window: gather+roll (ONCE) -> QKV GEMM all heads -> Q/K/V global bf16
__global__ __launch_bounds__(256) void qkv_kernel(
    const float* __restrict__ x_v, const us* __restrict__ qkvw,
    const float* __restrict__ qkv_b,
    us* __restrict__ Qg, us* __restrict__ Kg, us* __restrict__ Vg) {
  __shared__ __align__(16) us A[128 * 136];  // 34816 B
  int w = blockIdx.x;
  int b = w >> 8, wi = w & 255, wh = wi >> 4, ww = wi & 15;
  int tid = threadIdx.x;

  { // gather: rolled(p) = orig((p+4)&127)
    int token = tid >> 1, half = tid & 1;
    int t = token >> 6, n = token & 63, r = n >> 3, c = n & 7;
    int hs = (wh * 8 + r + 4) & 127, wsc = (ww * 8 + c + 4) & 127;
    const float* src = x_v + (size_t)((b * 2 + t) * 16384 + hs * 128 + wsc) * 128 + half * 64;
    us* dst = A + token * 136 + half * 64;
#pragma unroll
    for (int i = 0; i < 8; ++i) {
      float4 f0 = ((const float4*)src)[2 * i];
      float4 f1 = ((const float4*)src)[2 * i + 1];
      s16x8 v;
      v[0] = (short)f2bf(f0.x); v[1] = (short)f2bf(f0.y);
      v[2] = (short)f2bf(f0.z); v[3] = (short)f2bf(f0.w);
      v[4] = (short)f2bf(f1.x); v[5] = (short)f2bf(f1.y);
      v[6] = (short)f2bf(f1.z); v[7] = (short)f2bf(f1.w);
      *(s16x8*)(dst + i * 8) = v;
    }
  }
  __syncthreads();

  int lane = tid & 63, h = tid >> 6, quad = lane >> 4, c16 = lane & 15;
  size_t wb = (size_t)(w * 4 + h) * 4096;

#pragma unroll
  for (int p = 0; p < 2; ++p) {  // row passes: 64 rows each
    int rb = p * 64;
    f32x4 acc[4][6];
#pragma unroll
    for (int mi = 0; mi < 4; ++mi)
#pragma unroll
      for (int ni = 0; ni < 6; ++ni) acc[mi][ni] = (f32x4){0.f, 0.f, 0.f, 0.f};
#pragma unroll
    for (int ks = 0; ks < 4; ++ks) {
      int k0 = ks * 32;
      s16x8 af[4];
#pragma unroll
      for (int mi = 0; mi < 4; ++mi)
        af[mi] = ld8(A + (rb + mi * 16 + c16) * 136 + k0 + quad * 8);
#pragma unroll
      for (int ni = 0; ni < 6; ++ni) {
        int gcol = (ni >> 1) * 128 + h * 32 + (ni & 1) * 16 + c16;
        s16x8 bf = ld8(qkvw + ((((k0 >> 3) + quad) * 384 + gcol) << 3));
#pragma unroll
        for (int mi = 0; mi < 4; ++mi) acc[mi][ni] = MFMA(af[mi], bf, acc[mi][ni]);
      }
    }
#pragma unroll
    for (int ni = 0; ni < 6; ++ni) {
      int part = ni >> 1, colh = (ni & 1) * 16 + c16;
      float bias = qkv_b[part * 128 + h * 32 + colh];
      if (part == 0) bias *= 0.17677669529663687f;
      us* dstp = (part == 0) ? Qg : (part == 1) ? Kg : Vg;
#pragma unroll
      for (int mi = 0; mi < 4; ++mi)
#pragma unroll
        for (int r = 0; r < 4; ++r) {
          int tok = rb + mi * 16 + quad * 4 + r;
          dstp[wb + tok * 32 + colh] = f2bf(acc[mi][ni][r] + bias);
        }
    }
  }
}

// ---------- K2: per (window, head) attention. rpb+mask baked into MFMA C-init.
__global__ __launch_bounds__(256) void attn_kernel3(
    const us* __restrict__ Qg, const us* __restrict__ Kg, const us* __restrict__ Vg,
    const us* __restrict__ rpbm, us* __restrict__ attn_out) {
  __shared__ __align__(16) unsigned char smem[45056];
  us* Kb = (us*)smem;                  // [128][40]  10240 B
  us* Vt = (us*)(smem + 10240);        // [32][136]   8704 B (V transposed)
  us* Rb = (us*)(smem + 18944);        // [64][68]    8704 B (rpb+mask bf16)
  // Pw per wave at 27648 + wv*4352    // [16][136]  17408 B

  int bid = blockIdx.x;
  int w = bid >> 2, h = bid & 3;
  int wi = w & 255, wh = wi >> 4, ww = wi & 15;
  int tid = threadIdx.x;
  size_t wb = (size_t)(w * 4 + h) * 4096;
  int clsid = ((wh == 15) ? 2 : 0) + ((ww == 15) ? 1 : 0);

  {  // stage K (row-major, stride 40), V^T, rpbm
    int row = tid >> 1, seg = (tid & 1) * 16;
    *(s16x8*)(Kb + row * 40 + seg) = ld8(Kg + wb + row * 32 + seg);
    *(s16x8*)(Kb + row * 40 + seg + 8) = ld8(Kg + wb + row * 32 + seg + 8);
    int tok = tid & 127, dbase = (tid >> 7) * 16;
    s16x8 v0 = ld8(Vg + wb + tok * 32 + dbase);
    s16x8 v1 = ld8(Vg + wb + tok * 32 + dbase + 8);
#pragma unroll
    for (int j = 0; j < 8; ++j) {
      Vt[(dbase + j) * 136 + tok] = (us)v0[j];
      Vt[(dbase + 8 + j) * 136 + tok] = (us)v1[j];
    }
    const us* rsrc = rpbm + (h * 4 + clsid) * 4096;
    int rr = tid >> 2, cseg = (tid & 3) * 16;
    *(s16x8*)(Rb + rr * 68 + cseg) = ld8(rsrc + rr * 64 + cseg);
    *(s16x8*)(Rb + rr * 68 + cseg + 8) = ld8(rsrc + rr * 64 + cseg + 8);
  }
  __syncthreads();

  int lane = tid & 63, wv = tid >> 6, quad = lane >> 4, c16 = lane & 15;
  us* Pw = (us*)(smem + 27648 + wv * 4352);

#pragma unroll
  for (int qc = 0; qc < 2; ++qc) {
    int q0 = wv * 32 + qc * 16;
    s16x8 aq = ld8(Qg + wb + (q0 + c16) * 32 + quad * 8);
    int nqv[4];
#pragma unroll
    for (int r = 0; r < 4; ++r) nqv[r] = (q0 + quad * 4 + r) & 63;

    f32x4 sacc[8];
#pragma unroll
    for (int nj = 0; nj < 8; ++nj) {
      int nk = (nj * 16 + c16) & 63;
      f32x4 ci;
#pragma unroll
      for (int r = 0; r < 4; ++r) ci[r] = bf2f(Rb[nqv[r] * 68 + nk]);
      s16x8 bk = ld8(Kb + (nj * 16 + c16) * 40 + quad * 8);
      sacc[nj] = MFMA(aq, bk, ci);  // S + rpb + mask
    }
    // softmax without max-subtraction (|scores| << 80, masked = -100 -> exp ~ 0)
    float sm[4] = {0.f, 0.f, 0.f, 0.f};
#pragma unroll
    for (int nj = 0; nj < 8; ++nj)
#pragma unroll
      for (int r = 0; r < 4; ++r) {
        float p = __expf(sacc[nj][r]);
        sacc[nj][r] = p;
        sm[r] += p;
      }
    float inv[4];
#pragma unroll
    for (int r = 0; r < 4; ++r) inv[r] = 1.f / qsum(sm[r]);
    // P -> per-wave LDS (C-layout -> A-layout round trip)
#pragma unroll
    for (int nj = 0; nj < 8; ++nj)
#pragma unroll
      for (int r = 0; r < 4; ++r)
        Pw[(quad * 4 + r) * 136 + nj * 16 + c16] = f2bf(sacc[nj][r] * inv[r]);
    lds_fence();
    // PV
    f32x4 oacc[2];
    oacc[0] = (f32x4){0.f, 0.f, 0.f, 0.f};
    oacc[1] = (f32x4){0.f, 0.f, 0.f, 0.f};
#pragma unroll
    for (int ks = 0; ks < 4; ++ks) {
      int k0 = ks * 32;
      s16x8 ap = ld8(Pw + c16 * 136 + k0 + quad * 8);
#pragma unroll
      for (int nt = 0; nt < 2; ++nt) {
        s16x8 bv = ld8(Vt + (nt * 16 + c16) * 136 + k0 + quad * 8);
        oacc[nt] = MFMA(ap, bv, oacc[nt]);
      }
    }
#pragma unroll
    for (int nt = 0; nt < 2; ++nt)
#pragma unroll
      for (int r = 0; r < 4; ++r) {
        int tok = q0 + quad * 4 + r;
        attn_out[((size_t)w * 128 + tok) * 128 + h * 32 + nt * 16 + c16] =
            f2bf(oacc[nt][r]);
      }
    lds_fence();  // Pw WAR before next qc
  }
}

// ---------- K3: fused proj+LN2+MLP+LN1; 128 tokens/block, wave owns 32 rows.
__global__ __launch_bounds__(256, 2) void fused_kernel4(
    const us* __restrict__ attn_ws, const us* __restrict__ projw,
    const float* __restrict__ proj_b, const float* __restrict__ x_v,
    const us* __restrict__ fc1w, const us* __restrict__ fc2w,
    const float* __restrict__ fc1_b, const float* __restrict__ fc2_b,
    const float* __restrict__ n2w, const float* __restrict__ n2b,
    const float* __restrict__ n1w, const float* __restrict__ n1b,
    float* __restrict__ out) {
  __shared__ __align__(16) unsigned char smem[54272];
  us* A = (us*)smem;  // [128][136] attn tile -> LN2'd x (each wave: own 32 rows)
  int w = blockIdx.x;
  int b = w >> 8, wi = w & 255, wh = wi >> 4, ww = wi & 15;
  int tid = threadIdx.x;
  int lane = tid & 63, wv = tid >> 6, quad = lane >> 4, c16 = lane & 15;
  int r0 = wv * 32;
  us* Hw = (us*)(smem + 34816 + wv * 4864);  // per-wave [32][76] gelu chunk

  {  // wave stages its own 32 rows
    int row = r0 + (lane >> 1), half = (lane & 1) * 64;
    const us* src = attn_ws + ((size_t)w * 128 + row) * 128 + half;
    us* dst = A + row * 136 + half;
#pragma unroll
    for (int i = 0; i < 8; ++i) *(s16x8*)(dst + i * 8) = ld8(src + i * 8);
  }

  // residual addresses + prefetch x_v (consumed after proj)
  size_t grow[2][4];
  float xv[2][4][8];
#pragma unroll
  for (int mi = 0; mi < 2; ++mi)
#pragma unroll
    for (int r = 0; r < 4; ++r) {
      int tt = r0 + mi * 16 + quad * 4 + r;
      int t = tt >> 6, n = tt & 63, rr = n >> 3, cc2 = n & 7;
      int hf = (wh * 8 + rr + 4) & 127, wf = (ww * 8 + cc2 + 4) & 127;
      grow[mi][r] = (size_t)((b * 2 + t) * 16384 + hf * 128 + wf) * 128;
#pragma unroll
      for (int ni = 0; ni < 8; ++ni) xv[mi][r][ni] = x_v[grow[mi][r] + ni * 16 + c16];
    }
  lds_fence();  // staging visible to own wave

  // ---- proj: 32 rows x 128 cols, K=128
  f32x4 y[2][8];
#pragma unroll
  for (int mi = 0; mi < 2; ++mi)
#pragma unroll
    for (int ni = 0; ni < 8; ++ni) y[mi][ni] = (f32x4){0.f, 0.f, 0.f, 0.f};
#pragma unroll
  for (int ks = 0; ks < 4; ++ks) {
    int k0 = ks * 32;
    s16x8 af[2];
#pragma unroll
    for (int mi = 0; mi < 2; ++mi)
      af[mi] = ld8(A + (r0 + mi * 16 + c16) * 136 + k0 + quad * 8);
#pragma unroll
    for (int ni = 0; ni < 8; ++ni) {
      s16x8 bf = ld8(projw + ((((k0 >> 3) + quad) * 128 + ni * 16 + c16) << 3));
#pragma unroll
      for (int mi = 0; mi < 2; ++mi) y[mi][ni] = MFMA(af[mi], bf, y[mi][ni]);
    }
  }

  // ---- y += proj_b + shortcut; LN2 (wave-local); LN2'd x -> A
#pragma unroll
  for (int mi = 0; mi < 2; ++mi) {
    float sum[4] = {0.f, 0.f, 0.f, 0.f}, sq[4] = {0.f, 0.f, 0.f, 0.f};
#pragma unroll
    for (int ni = 0; ni < 8; ++ni) {
      float pb = proj_b[ni * 16 + c16];
#pragma unroll
      for (int r = 0; r < 4; ++r) {
        float v = y[mi][ni][r] + pb + xv[mi][r][ni];
        y[mi][ni][r] = v;
        sum[r] += v; sq[r] += v * v;
      }
    }
#pragma unroll
    for (int r = 0; r < 4; ++r) {
      float s = qsum(sum[r]), q = qsum(sq[r]);
      float mean = s * 0.0078125f;
      float rstd = rsqrtf(q * 0.0078125f - mean * mean + 1e-5f);
      int m = r0 + mi * 16 + quad * 4 + r;
#pragma unroll
      for (int ni = 0; ni < 8; ++ni) {
        int col = ni * 16 + c16;
        A[m * 136 + col] = f2bf((y[mi][ni][r] - mean) * rstd * n2w[col] + n2b[col]);
      }
    }
  }
  lds_fence();

  // ---- MLP: 8 chunks of 64 hidden; fc1 -> gelu -> fc2, wave-local
  f32x4 o[2][8];
#pragma unroll
  for (int mi = 0; mi < 2; ++mi)
#pragma unroll
    for (int ni = 0; ni < 8; ++ni) o[mi][ni] = (f32x4){0.f, 0.f, 0.f, 0.f};

#pragma unroll
  for (int cc = 0; cc < 8; ++cc) {
    f32x4 f[2][4];
#pragma unroll
    for (int mi = 0; mi < 2; ++mi)
#pragma unroll
      for (int ni = 0; ni < 4; ++ni) f[mi][ni] = (f32x4){0.f, 0.f, 0.f, 0.f};
#pragma unroll
    for (int ks = 0; ks < 4; ++ks) {
      int k0 = ks * 32;
      s16x8 af[2];
#pragma unroll
      for (int mi = 0; mi < 2; ++mi)
        af[mi] = ld8(A + (r0 + mi * 16 + c16) * 136 + k0 + quad * 8);
#pragma unroll
      for (int ni = 0; ni < 4; ++ni) {
        s16x8 bf = ld8(fc1w + ((((k0 >> 3) + quad) * 512 + cc * 64 + ni * 16 + c16) << 3));
#pragma unroll
        for (int mi = 0; mi < 2; ++mi) f[mi][ni] = MFMA(af[mi], bf, f[mi][ni]);
      }
    }
#pragma unroll
    for (int mi = 0; mi < 2; ++mi)
#pragma unroll
      for (int ni = 0; ni < 4; ++ni) {
        float bb = fc1_b[cc * 64 + ni * 16 + c16];
#pragma unroll
        for (int r = 0; r < 4; ++r) {
          float u = f[mi][ni][r] + bb;
          Hw[(mi * 16 + quad * 4 + r) * 76 + ni * 16 + c16] = f2bf(gelu_fast(u));
        }
      }
    lds_fence();
#pragma unroll
    for (int ks2 = 0; ks2 < 2; ++ks2) {
      s16x8 ah[2];
#pragma unroll
      for (int mi = 0; mi < 2; ++mi)
        ah[mi] = ld8(Hw + (mi * 16 + c16) * 76 + ks2 * 32 + quad * 8);
#pragma unroll
      for (int ni = 0; ni < 8; ++ni) {
        s16x8 bf = ld8(fc2w + (((cc * 8 + ks2 * 4 + quad) * 128 + ni * 16 + c16) << 3));
#pragma unroll
        for (int mi = 0; mi < 2; ++mi) o[mi][ni] = MFMA(ah[mi], bf, o[mi][ni]);
      }
    }
    lds_fence();  // Hw WAR before next chunk
  }

  // ---- z = fc2 + bias + y; LN1; scatter store
#pragma unroll
  for (int mi = 0; mi < 2; ++mi) {
    float s1[4] = {0.f, 0.f, 0.f, 0.f}, q1[4] = {0.f, 0.f, 0.f, 0.f};
#pragma unroll
    for (int ni = 0; ni < 8; ++ni) {
      float fb = fc2_b[ni * 16 + c16];
#pragma unroll
      for (int r = 0; r < 4; ++r) {
        float v = o[mi][ni][r] + fb + y[mi][ni][r];
        y[mi][ni][r] = v;
        s1[r] += v; q1[r] += v * v;
      }
    }
#pragma unroll
    for (int r = 0; r < 4; ++r) {
      float s = qsum(s1[r]), q = qsum(q1[r]);
      float mean = s * 0.0078125f;
      float rstd = rsqrtf(q * 0.0078125f - mean * mean + 1e-5f);
#pragma unroll
      for (int ni = 0; ni < 8; ++ni) {
        int col = ni * 16 + c16;
        out[grow[mi][r] + col] = (y[mi][ni][r] - mean) * rstd * n1w[col] + n1b[col];
      }
    }
  }
}

extern "C" void kernel_launch(void* const* d_in, const int* in_sizes, int n_in,
                              void* d_out, int out_size, void* d_ws, size_t ws_size,
                              hipStream_t stream) {
  const float* x_v   = (const float*)d_in[0];
  const float* qkv_w = (const float*)d_in[1];
  const float* qkv_b = (const float*)d_in[2];
  const float* proj_w = (const float*)d_in[3];
  const float* proj_b = (const float*)d_in[4];
  const float* rpb_t = (const float*)d_in[5];
  const float* n1w = (const float*)d_in[6];
  const float* n1b = (const float*)d_in[7];
  const float* n2w = (const float*)d_in[8];
  const float* n2b = (const float*)d_in[9];
  const float* fc1_w = (const float*)d_in[10];
  const float* fc1_b = (const float*)d_in[11];
  const float* fc2_w = (const float*)d_in[12];
  const float* fc2_b = (const float*)d_in[13];

  char* ws = (char*)d_ws;
  us* qkvw    = (us*)(ws + 0);         //  98304
  us* projw   = (us*)(ws + 98304);     //  32768
  us* fc1w    = (us*)(ws + 131072);    // 131072
  us* fc2w    = (us*)(ws + 262144);    // 131072
  us* rpbm    = (us*)(ws + 393216);    // 131072
  us* Qg      = (us*)(ws + 524288);    // 8388608
  us* Kg      = (us*)(ws + 8912896);   // 8388608
  us* Vg      = (us*)(ws + 17301504);  // 8388608
  us* attn_ws = (us*)(ws + 25690112);  // 33554432

  prep_kernel<<<1024, 256, 0, stream>>>(qkv_w, proj_w, fc1_w, fc2_w, rpb_t,
                                        qkvw, projw, fc1w, fc2w, rpbm);
  qkv_kernel<<<1024, 256, 0, stream>>>(x_v, qkvw, qkv_b, Qg, Kg, Vg);
  attn_kernel3<<<4096, 256, 0, stream>>>(Qg, Kg, Vg, rpbm, attn_ws);
  fused_kernel4<<<1024, 256, 0, stream>>>(attn_ws, projw, proj_b, x_v,
                                          fc1w, fc2w, fc1_b, fc2_b,
                                          n2w, n2b, n1w, n1b, (float*)d_out);
}